// Round 2
// baseline (726.089 us; speedup 1.0000x reference)
//
#include <hip/hip_runtime.h>
#include <hip/hip_bf16.h>
#include <stdint.h>

#define D_MODEL 512
#define N_EXP 8
#define D_FF 2048
#define NTOK 8192
#define TM 256
#define MAX_TILES 72                 /* 16384/256 + 8 */
#define NEPAD (MAX_TILES*TM)         /* 18432 */
#define BK 64

typedef __attribute__((ext_vector_type(8))) short short8;
typedef __attribute__((ext_vector_type(4))) float f32x4;

struct Ctrl {
  int cnt[8];
  int cursor[8];
  int offpad[16];
  int ntiles;
  int pad[3];
  int texp[MAX_TILES];
};

__device__ __forceinline__ unsigned short f2bf(float f){
  unsigned u = __float_as_uint(f);
  u += 0x7FFFu + ((u>>16)&1u);          // RNE
  return (unsigned short)(u>>16);
}

__device__ __forceinline__ short8 pack8(float4 a, float4 b){
  short8 o;
  o[0]=(short)f2bf(a.x); o[1]=(short)f2bf(a.y); o[2]=(short)f2bf(a.z); o[3]=(short)f2bf(a.w);
  o[4]=(short)f2bf(b.x); o[5]=(short)f2bf(b.y); o[6]=(short)f2bf(b.z); o[7]=(short)f2bf(b.w);
  return o;
}

__device__ __forceinline__ void gload16(const void* g, void* l){
  __builtin_amdgcn_global_load_lds((const __attribute__((address_space(1))) unsigned int*)g,
                                   (__attribute__((address_space(3))) unsigned int*)l, 16, 0, 0);
}

// ---------------- f32 -> bf16 ----------------
__global__ void __launch_bounds__(256)
cvt_kernel(const float* __restrict__ src, unsigned short* __restrict__ dst, int n){
  int i = (blockIdx.x*256 + threadIdx.x)*8;
  if(i >= n) return;
  float4 a = *(const float4*)(src+i);
  float4 b = *(const float4*)(src+i+4);
  *(short8*)(dst+i) = pack8(a,b);
}

// ---------------- gating: logits->softmax->top2 ----------------
__global__ void __launch_bounds__(256)
gate_kernel(const float* __restrict__ x, const float* __restrict__ gw,
            int* __restrict__ tok_e, float* __restrict__ tok_s,
            Ctrl* __restrict__ c, float* __restrict__ Ppart){
  __shared__ float gws[N_EXP*D_MODEL];
  __shared__ float pblk[4][8];
  __shared__ int cblk[8];
  int tid = threadIdx.x;
  for(int i=tid; i<N_EXP*D_MODEL; i+=256) gws[i]=gw[i];
  if(tid<8) cblk[tid]=0;
  __syncthreads();
  int wave = tid>>6, lane = tid&63;
  int t = blockIdx.x*4 + wave;
  const float* xr = x + (size_t)t*D_MODEL + lane*8;
  float4 xa = *(const float4*)xr;
  float4 xb = *(const float4*)(xr+4);
  float le[8];
  #pragma unroll
  for(int e=0;e<8;e++){
    const float* g = gws + e*D_MODEL + lane*8;
    float4 ga = *(const float4*)g;
    float4 gb = *(const float4*)(g+4);
    le[e] = xa.x*ga.x + xa.y*ga.y + xa.z*ga.z + xa.w*ga.w
          + xb.x*gb.x + xb.y*gb.y + xb.z*gb.z + xb.w*gb.w;
  }
  #pragma unroll
  for(int e=0;e<8;e++){
    float v = le[e];
    #pragma unroll
    for(int off=1; off<64; off<<=1) v += __shfl_xor(v, off);
    le[e]=v;
  }
  float mx = le[0];
  #pragma unroll
  for(int e=1;e<8;e++) mx = fmaxf(mx, le[e]);
  float p[8], s=0.f;
  #pragma unroll
  for(int e=0;e<8;e++){ p[e]=__expf(le[e]-mx); s+=p[e]; }
  float inv = 1.0f/s;
  #pragma unroll
  for(int e=0;e<8;e++) p[e]*=inv;
  int e0=0; float s0=p[0];
  #pragma unroll
  for(int e=1;e<8;e++) if(p[e]>s0){e0=e;s0=p[e];}
  int e1=-1; float s1=-1.f;
  #pragma unroll
  for(int e=0;e<8;e++) if(e!=e0 && p[e]>s1){e1=e;s1=p[e];}
  if(lane==0){
    tok_e[2*t]=e0; tok_e[2*t+1]=e1;
    tok_s[2*t]=s0; tok_s[2*t+1]=s1;
    atomicAdd(&cblk[e0],1); atomicAdd(&cblk[e1],1);
    #pragma unroll
    for(int e=0;e<8;e++) pblk[wave][e]=p[e];
  }
  __syncthreads();
  if(tid<8){
    atomicAdd(&c->cnt[tid], cblk[tid]);
    Ppart[blockIdx.x*8+tid] = pblk[0][tid]+pblk[1][tid]+pblk[2][tid]+pblk[3][tid];
  }
}

// ---------------- scan: offsets, tile map, aux loss ----------------
__global__ void __launch_bounds__(256)
scan_kernel(Ctrl* __restrict__ c, const float* __restrict__ Ppart, float* __restrict__ out){
  __shared__ float red[256];
  __shared__ float tot[8];
  int tid = threadIdx.x;
  for(int e=0;e<8;e++){
    float v=0.f;
    for(int i=tid;i<2048;i+=256) v += Ppart[i*8+e];
    red[tid]=v; __syncthreads();
    for(int s=128;s>0;s>>=1){ if(tid<s) red[tid]+=red[tid+s]; __syncthreads(); }
    if(tid==0) tot[e]=red[0];
    __syncthreads();
  }
  if(tid==0){
    int o=0, tc=0;
    float aux=0.f;
    for(int e=0;e<8;e++){
      c->offpad[e]=o;
      int nt = (c->cnt[e]+TM-1)/TM;
      for(int i=0;i<nt;i++) c->texp[tc++]=e;
      o += nt*TM;
      c->cursor[e]=0;
      aux += ((float)c->cnt[e]/(float)NTOK) * (tot[e]/(float)NTOK);
    }
    c->offpad[8]=o;
    c->ntiles=tc;
    out[(size_t)NTOK*D_MODEL] = 8.0f*0.01f*aux;   // aux_loss slot
  }
}

// ---------------- scatter tokens into per-expert entry lists ----------------
__global__ void __launch_bounds__(256)
scatter_kernel(const int* __restrict__ tok_e, const float* __restrict__ tok_s,
               Ctrl* __restrict__ c, int* __restrict__ etok, float* __restrict__ escl){
  int t = blockIdx.x*256 + threadIdx.x;
  if(t >= NTOK) return;
  #pragma unroll
  for(int k=0;k<2;k++){
    int e = tok_e[2*t+k];
    int pos = atomicAdd(&c->cursor[e],1);
    int i = c->offpad[e]+pos;
    etok[i]=t; escl[i]=tok_s[2*t+k];
  }
}

#define PIPE_WAIT(LAST)                                              \
  if(!(LAST)) asm volatile("s_waitcnt vmcnt(8)" ::: "memory");       \
  else        asm volatile("s_waitcnt vmcnt(0)" ::: "memory");       \
  __builtin_amdgcn_sched_barrier(0);                                 \
  __builtin_amdgcn_s_barrier();                                      \
  __builtin_amdgcn_sched_barrier(0);

#define PIPE_END()                                                   \
  __builtin_amdgcn_sched_barrier(0);                                 \
  __builtin_amdgcn_s_barrier();                                      \
  __builtin_amdgcn_sched_barrier(0);

// ---------------- phase A: G = silu(X W1^T) * (X V1^T) ----------------
// tile = 256 entries x 128 ff (both mats). 8 waves (2M x 4N), wave = 128r x 64effc.
__global__ void __launch_bounds__(512,2)
expA_kernel(const unsigned short* __restrict__ Xb, const unsigned short* __restrict__ W1b,
            const unsigned short* __restrict__ V1b, const int* __restrict__ etok,
            const Ctrl* __restrict__ c, unsigned short* __restrict__ G){
  __shared__ short8 As[2][2048];   // [buf][row*8 + chunk], chunk XOR-swizzled by row&7
  __shared__ short8 Bs[2][2048];   // [buf][mat*1024 + frow*8 + chunk]
  int tile = blockIdx.x;
  if(tile >= c->ntiles) return;
  int e = c->texp[tile];
  int base = tile*TM;
  int fbase = blockIdx.y*128;
  int tid = threadIdx.x;

  // staging: slot s = tid + j*512 -> row = s>>3, chunk = tid&7 (inverse-swizzled source)
  int r0 = tid>>3;
  int cs = (tid&7) ^ (r0&7);
  int t0 = etok[base + r0];
  int t1 = etok[base + 64 + r0];
  int t2 = etok[base + 128 + r0];
  int t3 = etok[base + 192 + r0];
  const unsigned short* sA0 = Xb + (size_t)t0*D_MODEL + cs*8;
  const unsigned short* sA1 = Xb + (size_t)t1*D_MODEL + cs*8;
  const unsigned short* sA2 = Xb + (size_t)t2*D_MODEL + cs*8;
  const unsigned short* sA3 = Xb + (size_t)t3*D_MODEL + cs*8;
  const unsigned short* WE = W1b + (size_t)e*(D_FF*D_MODEL);
  const unsigned short* VE = V1b + (size_t)e*(D_FF*D_MODEL);
  const unsigned short* sB0 = WE + (size_t)(fbase+r0)*D_MODEL + cs*8;
  const unsigned short* sB1 = WE + (size_t)(fbase+64+r0)*D_MODEL + cs*8;
  const unsigned short* sB2 = VE + (size_t)(fbase+r0)*D_MODEL + cs*8;
  const unsigned short* sB3 = VE + (size_t)(fbase+64+r0)*D_MODEL + cs*8;
  int w64 = tid & ~63;

  int lane = tid&63, lrow = lane&15, lk = lane>>4;
  int wid = tid>>6, wr = wid>>2, wc = wid&3;
  int sw = lrow&7;

  f32x4 hacc[8][2], vacc[8][2];
  #pragma unroll
  for(int mi=0;mi<8;mi++)
    #pragma unroll
    for(int nj=0;nj<2;nj++){
      hacc[mi][nj]=(f32x4){0.f,0.f,0.f,0.f};
      vacc[mi][nj]=(f32x4){0.f,0.f,0.f,0.f};
    }

  auto STAGE = [&](int b, int t){
    size_t off = (size_t)t*BK;
    gload16(sA0+off, &As[b][w64]);
    gload16(sA1+off, &As[b][512+w64]);
    gload16(sA2+off, &As[b][1024+w64]);
    gload16(sA3+off, &As[b][1536+w64]);
    gload16(sB0+off, &Bs[b][w64]);
    gload16(sB1+off, &Bs[b][512+w64]);
    gload16(sB2+off, &Bs[b][1024+w64]);
    gload16(sB3+off, &Bs[b][1536+w64]);
  };

  STAGE(0,0);
  for(int t=0;t<8;t++){
    int cur = t&1;
    if(t<7) STAGE(cur^1, t+1);
    PIPE_WAIT(t==7);
    #pragma unroll
    for(int kk=0;kk<2;kk++){
      int ch = (kk*4+lk) ^ sw;
      short8 a[8], bw[2], bv[2];
      #pragma unroll
      for(int mi=0;mi<8;mi++)
        a[mi] = As[cur][(wr*128+mi*16+lrow)*8 + ch];
      #pragma unroll
      for(int nj=0;nj<2;nj++){
        int fr = wc*32+nj*16+lrow;
        bw[nj] = Bs[cur][fr*8 + ch];
        bv[nj] = Bs[cur][1024 + fr*8 + ch];
      }
      #pragma unroll
      for(int mi=0;mi<8;mi++)
        #pragma unroll
        for(int nj=0;nj<2;nj++){
          hacc[mi][nj] = __builtin_amdgcn_mfma_f32_16x16x32_bf16(a[mi], bw[nj], hacc[mi][nj],0,0,0);
          vacc[mi][nj] = __builtin_amdgcn_mfma_f32_16x16x32_bf16(a[mi], bv[nj], vacc[mi][nj],0,0,0);
        }
    }
    PIPE_END();
  }

  #pragma unroll
  for(int mi=0;mi<8;mi++){
    int m = base + wr*128 + mi*16 + lk*4;
    #pragma unroll
    for(int nj=0;nj<2;nj++){
      int f = fbase + wc*32 + nj*16 + lrow;
      #pragma unroll
      for(int r=0;r<4;r++){
        float h = hacc[mi][nj][r], vv = vacc[mi][nj][r];
        float g = (h/(1.0f+__expf(-h)))*vv;
        G[(size_t)(m+r)*D_FF + f] = f2bf(g);
      }
    }
  }
}

// ---------------- phase B: Y = G W2^T, scatter-add scale*Y ----------------
// tile = 256 entries x 256 n-cols, K-split 4 (512 K each). 8 waves, wave = 128r x 64c.
__global__ void __launch_bounds__(512,2)
expB_kernel(const unsigned short* __restrict__ G, const unsigned short* __restrict__ W2b,
            const int* __restrict__ etok, const float* __restrict__ escl,
            const Ctrl* __restrict__ c, float* __restrict__ out){
  __shared__ short8 Gs[2][2048];
  __shared__ short8 Bs[2][2048];
  __shared__ int stok[256];
  __shared__ float sscl[256];
  int tile = blockIdx.x;
  if(tile >= c->ntiles) return;
  int e = c->texp[tile];
  int base = tile*TM;
  int nbase = blockIdx.y*256;
  int kbase = blockIdx.z*512;
  int tid = threadIdx.x;
  if(tid<256){ stok[tid]=etok[base+tid]; sscl[tid]=escl[base+tid]; }

  int r0 = tid>>3;
  int cs = (tid&7) ^ (r0&7);
  const unsigned short* sA0 = G + (size_t)(base+r0)*D_FF + kbase + cs*8;
  const unsigned short* sA1 = G + (size_t)(base+64+r0)*D_FF + kbase + cs*8;
  const unsigned short* sA2 = G + (size_t)(base+128+r0)*D_FF + kbase + cs*8;
  const unsigned short* sA3 = G + (size_t)(base+192+r0)*D_FF + kbase + cs*8;
  const unsigned short* W2E = W2b + (size_t)e*(D_MODEL*D_FF);
  const unsigned short* sB0 = W2E + (size_t)(nbase+r0)*D_FF + kbase + cs*8;
  const unsigned short* sB1 = W2E + (size_t)(nbase+64+r0)*D_FF + kbase + cs*8;
  const unsigned short* sB2 = W2E + (size_t)(nbase+128+r0)*D_FF + kbase + cs*8;
  const unsigned short* sB3 = W2E + (size_t)(nbase+192+r0)*D_FF + kbase + cs*8;
  int w64 = tid & ~63;

  int lane = tid&63, lrow = lane&15, lk = lane>>4;
  int wid = tid>>6, wr = wid>>2, wc = wid&3;
  int sw = lrow&7;

  f32x4 acc[8][4];
  #pragma unroll
  for(int mi=0;mi<8;mi++)
    #pragma unroll
    for(int nj=0;nj<4;nj++) acc[mi][nj]=(f32x4){0.f,0.f,0.f,0.f};

  auto STAGE = [&](int b, int t){
    size_t off = (size_t)t*BK;
    gload16(sA0+off, &Gs[b][w64]);
    gload16(sA1+off, &Gs[b][512+w64]);
    gload16(sA2+off, &Gs[b][1024+w64]);
    gload16(sA3+off, &Gs[b][1536+w64]);
    gload16(sB0+off, &Bs[b][w64]);
    gload16(sB1+off, &Bs[b][512+w64]);
    gload16(sB2+off, &Bs[b][1024+w64]);
    gload16(sB3+off, &Bs[b][1536+w64]);
  };

  STAGE(0,0);
  for(int t=0;t<8;t++){
    int cur = t&1;
    if(t<7) STAGE(cur^1, t+1);
    PIPE_WAIT(t==7);
    #pragma unroll
    for(int kk=0;kk<2;kk++){
      int ch = (kk*4+lk) ^ sw;
      short8 a[8], b[4];
      #pragma unroll
      for(int mi=0;mi<8;mi++)
        a[mi] = Gs[cur][(wr*128+mi*16+lrow)*8 + ch];
      #pragma unroll
      for(int nj=0;nj<4;nj++){
        int nr = wc*64+nj*16+lrow;
        b[nj] = Bs[cur][nr*8 + ch];
      }
      #pragma unroll
      for(int mi=0;mi<8;mi++)
        #pragma unroll
        for(int nj=0;nj<4;nj++)
          acc[mi][nj] = __builtin_amdgcn_mfma_f32_16x16x32_bf16(a[mi], b[nj], acc[mi][nj],0,0,0);
    }
    PIPE_END();
  }

  #pragma unroll
  for(int mi=0;mi<8;mi++){
    #pragma unroll
    for(int r=0;r<4;r++){
      int m = wr*128 + mi*16 + lk*4 + r;
      int tokm = stok[m];
      float sc = sscl[m];
      #pragma unroll
      for(int nj=0;nj<4;nj++){
        int n = nbase + wc*64 + nj*16 + lrow;
        atomicAdd(out + (size_t)tokm*D_MODEL + n, sc*acc[mi][nj][r]);
      }
    }
  }
}

extern "C" void kernel_launch(void* const* d_in, const int* in_sizes, int n_in,
                              void* d_out, int out_size, void* d_ws, size_t ws_size,
                              hipStream_t stream) {
  (void)in_sizes; (void)n_in;
  const float* x  = (const float*)d_in[0];
  const float* gw = (const float*)d_in[1];
  const float* W1 = (const float*)d_in[2];
  const float* V1 = (const float*)d_in[3];
  const float* W2 = (const float*)d_in[4];
  float* out = (float*)d_out;

  const size_t WSZ = (size_t)N_EXP*D_FF*D_MODEL;     // 8.39M elems per weight
  const size_t XSZ = (size_t)NTOK*D_MODEL;           // 4.19M
  char* ws = (char*)d_ws;
  size_t off = 0;
  unsigned short* W1b = (unsigned short*)(ws+off); off += WSZ*2;
  unsigned short* V1b = (unsigned short*)(ws+off); off += WSZ*2;
  unsigned short* Xb  = (unsigned short*)(ws+off); off += XSZ*2;
  unsigned short* G   = (unsigned short*)(ws+off); off += (size_t)NEPAD*D_FF*2;
  int*   etok  = (int*)(ws+off);   size_t entry_off = off; off += (size_t)NEPAD*4;
  float* escl  = (float*)(ws+off); off += (size_t)NEPAD*4;
  size_t entry_bytes = off - entry_off;
  int*   tok_e = (int*)(ws+off);   off += (size_t)NTOK*2*4;
  float* tok_s = (float*)(ws+off); off += (size_t)NTOK*2*4;
  float* Ppart = (float*)(ws+off); off += (size_t)2048*8*4;
  Ctrl*  ctrl  = (Ctrl*)(ws+off);  off += sizeof(Ctrl);
  unsigned short* W2b = W1b;   // reuse W1b's region after expA (converted post-expA)
  if(ws_size < off) return;

  hipMemsetAsync(d_out, 0, (size_t)out_size*sizeof(float), stream);
  hipMemsetAsync(ws+entry_off, 0, entry_bytes, stream);
  hipMemsetAsync(ctrl, 0, sizeof(Ctrl), stream);

  int nw = (int)WSZ;
  cvt_kernel<<<nw/(256*8), 256, 0, stream>>>(W1, W1b, nw);
  cvt_kernel<<<nw/(256*8), 256, 0, stream>>>(V1, V1b, nw);
  cvt_kernel<<<(int)XSZ/(256*8), 256, 0, stream>>>(x, Xb, (int)XSZ);

  gate_kernel<<<NTOK/4, 256, 0, stream>>>(x, gw, tok_e, tok_s, ctrl, Ppart);
  scan_kernel<<<1, 256, 0, stream>>>(ctrl, Ppart, out);
  scatter_kernel<<<NTOK/256, 256, 0, stream>>>(tok_e, tok_s, ctrl, etok, escl);

  expA_kernel<<<dim3(MAX_TILES, D_FF/128), 512, 0, stream>>>(Xb, W1b, V1b, etok, ctrl, G);
  cvt_kernel<<<nw/(256*8), 256, 0, stream>>>(W2, W2b, nw);   // into W1b region
  expB_kernel<<<dim3(MAX_TILES, 2, 4), 512, 0, stream>>>(G, W2b, etok, escl, ctrl, out);
}

// Round 3
// 370.190 us; speedup vs baseline: 1.9614x; 1.9614x over previous
//
#include <hip/hip_runtime.h>
#include <hip/hip_bf16.h>
#include <stdint.h>

#define D_MODEL 512
#define N_EXP 8
#define D_FF 2048
#define NTOK 8192
#define TM 256
#define MAX_TILES 72                 /* ceil(16384/256) + 8 */
#define NEPAD (MAX_TILES*TM)         /* 18432 */
#define BK 64

typedef __attribute__((ext_vector_type(8))) short short8;
typedef __attribute__((ext_vector_type(4))) float f32x4;

struct Ctrl {
  int cnt[8];
  int cursor[8];
  int offpad[16];
  int ntiles;
  int pad[3];
  int texp[MAX_TILES];
};

__device__ __forceinline__ unsigned short f2bf(float f){
  unsigned u = __float_as_uint(f);
  u += 0x7FFFu + ((u>>16)&1u);          // RNE
  return (unsigned short)(u>>16);
}
__device__ __forceinline__ float bf2f(unsigned short v){
  return __uint_as_float(((unsigned)v)<<16);
}

__device__ __forceinline__ short8 pack8(float4 a, float4 b){
  short8 o;
  o[0]=(short)f2bf(a.x); o[1]=(short)f2bf(a.y); o[2]=(short)f2bf(a.z); o[3]=(short)f2bf(a.w);
  o[4]=(short)f2bf(b.x); o[5]=(short)f2bf(b.y); o[6]=(short)f2bf(b.z); o[7]=(short)f2bf(b.w);
  return o;
}

__device__ __forceinline__ void gload16(const void* g, void* l){
  __builtin_amdgcn_global_load_lds((const __attribute__((address_space(1))) unsigned int*)g,
                                   (__attribute__((address_space(3))) unsigned int*)l, 16, 0, 0);
}

// ---------------- f32 -> bf16 ----------------
__global__ void __launch_bounds__(256)
cvt_kernel(const float* __restrict__ src, unsigned short* __restrict__ dst, int n){
  int i = (blockIdx.x*256 + threadIdx.x)*8;
  if(i >= n) return;
  float4 a = *(const float4*)(src+i);
  float4 b = *(const float4*)(src+i+4);
  *(short8*)(dst+i) = pack8(a,b);
}

// ---------------- gating: logits->softmax->top2 (+x->bf16) ----------------
__global__ void __launch_bounds__(256)
gate_kernel(const float* __restrict__ x, const float* __restrict__ gw,
            int* __restrict__ tok_e, float* __restrict__ tok_s,
            Ctrl* __restrict__ c, float* __restrict__ Ppart,
            unsigned short* __restrict__ Xb){
  __shared__ float gws[N_EXP*D_MODEL];
  __shared__ float pblk[4][8];
  __shared__ int cblk[8];
  int tid = threadIdx.x;
  for(int i=tid; i<N_EXP*D_MODEL; i+=256) gws[i]=gw[i];
  if(tid<8) cblk[tid]=0;
  __syncthreads();
  int wave = tid>>6, lane = tid&63;
  int t = blockIdx.x*4 + wave;
  const float* xr = x + (size_t)t*D_MODEL + lane*8;
  float4 xa = *(const float4*)xr;
  float4 xb = *(const float4*)(xr+4);
  *(short8*)(Xb + (size_t)t*D_MODEL + lane*8) = pack8(xa,xb);
  float le[8];
  #pragma unroll
  for(int e=0;e<8;e++){
    const float* g = gws + e*D_MODEL + lane*8;
    float4 ga = *(const float4*)g;
    float4 gb = *(const float4*)(g+4);
    le[e] = xa.x*ga.x + xa.y*ga.y + xa.z*ga.z + xa.w*ga.w
          + xb.x*gb.x + xb.y*gb.y + xb.z*gb.z + xb.w*gb.w;
  }
  #pragma unroll
  for(int e=0;e<8;e++){
    float v = le[e];
    #pragma unroll
    for(int off=1; off<64; off<<=1) v += __shfl_xor(v, off);
    le[e]=v;
  }
  float mx = le[0];
  #pragma unroll
  for(int e=1;e<8;e++) mx = fmaxf(mx, le[e]);
  float p[8], s=0.f;
  #pragma unroll
  for(int e=0;e<8;e++){ p[e]=__expf(le[e]-mx); s+=p[e]; }
  float inv = 1.0f/s;
  #pragma unroll
  for(int e=0;e<8;e++) p[e]*=inv;
  int e0=0; float s0=p[0];
  #pragma unroll
  for(int e=1;e<8;e++) if(p[e]>s0){e0=e;s0=p[e];}
  int e1=-1; float s1=-1.f;
  #pragma unroll
  for(int e=0;e<8;e++) if(e!=e0 && p[e]>s1){e1=e;s1=p[e];}
  if(lane==0){
    tok_e[2*t]=e0; tok_e[2*t+1]=e1;
    tok_s[2*t]=s0; tok_s[2*t+1]=s1;
    atomicAdd(&cblk[e0],1); atomicAdd(&cblk[e1],1);
    #pragma unroll
    for(int e=0;e<8;e++) pblk[wave][e]=p[e];
  }
  __syncthreads();
  if(tid<8){
    atomicAdd(&c->cnt[tid], cblk[tid]);
    Ppart[blockIdx.x*8+tid] = pblk[0][tid]+pblk[1][tid]+pblk[2][tid]+pblk[3][tid];
  }
}

// ---------------- scan: offsets, tile map, aux loss ----------------
__global__ void __launch_bounds__(256)
scan_kernel(Ctrl* __restrict__ c, const float* __restrict__ Ppart, float* __restrict__ out){
  __shared__ float red[256];
  __shared__ float tot[8];
  int tid = threadIdx.x;
  for(int e=0;e<8;e++){
    float v=0.f;
    for(int i=tid;i<2048;i+=256) v += Ppart[i*8+e];
    red[tid]=v; __syncthreads();
    for(int s=128;s>0;s>>=1){ if(tid<s) red[tid]+=red[tid+s]; __syncthreads(); }
    if(tid==0) tot[e]=red[0];
    __syncthreads();
  }
  if(tid==0){
    int o=0, tc=0;
    float aux=0.f;
    for(int e=0;e<8;e++){
      c->offpad[e]=o;
      int nt = (c->cnt[e]+TM-1)/TM;
      for(int i=0;i<nt;i++) c->texp[tc++]=e;
      o += nt*TM;
      c->cursor[e]=0;
      aux += ((float)c->cnt[e]/(float)NTOK) * (tot[e]/(float)NTOK);
    }
    c->offpad[8]=o;
    c->ntiles=tc;
    out[(size_t)NTOK*D_MODEL] = 8.0f*0.01f*aux;   // aux_loss slot
  }
}

// ---------------- scatter tokens into per-expert entry lists ----------------
__global__ void __launch_bounds__(256)
scatter_kernel(const int* __restrict__ tok_e, const float* __restrict__ tok_s,
               Ctrl* __restrict__ c, int* __restrict__ etok, float* __restrict__ escl,
               int* __restrict__ pos){
  int t = blockIdx.x*256 + threadIdx.x;
  if(t >= NTOK) return;
  #pragma unroll
  for(int k=0;k<2;k++){
    int e = tok_e[2*t+k];
    int p = atomicAdd(&c->cursor[e],1);
    int i = c->offpad[e]+p;
    etok[i]=t; escl[i]=tok_s[2*t+k];
    pos[2*t+k]=i;
  }
}

#define PIPE_WAIT_N(NSTR, LAST)                                      \
  if(!(LAST)) asm volatile("s_waitcnt vmcnt(" NSTR ")" ::: "memory");\
  else        asm volatile("s_waitcnt vmcnt(0)" ::: "memory");       \
  __builtin_amdgcn_sched_barrier(0);                                 \
  __builtin_amdgcn_s_barrier();                                      \
  __builtin_amdgcn_sched_barrier(0);

#define PIPE_END()                                                   \
  __builtin_amdgcn_sched_barrier(0);                                 \
  __builtin_amdgcn_s_barrier();                                      \
  __builtin_amdgcn_sched_barrier(0);

// ---------------- phase A: G = silu(X W1^T) * (X V1^T) ----------------
// tile = 256 entries x 128 ff (both mats). 8 waves (2M x 4N), wave = 128r x 32f.
__global__ void __launch_bounds__(512,2)
expA_kernel(const unsigned short* __restrict__ Xb, const unsigned short* __restrict__ W1b,
            const unsigned short* __restrict__ V1b, const int* __restrict__ etok,
            const Ctrl* __restrict__ c, unsigned short* __restrict__ G){
  __shared__ short8 As[2][2048];   // [buf][row*8 + chunk], chunk XOR-swizzled by row&7
  __shared__ short8 Bs[2][2048];   // [buf][mat*1024 + frow*8 + chunk]
  int bid = blockIdx.x;                  // 0..1151, 1152 = 8*144
  int w = (bid & 7)*144 + (bid >> 3);    // XCD-chunked bijective swizzle
  int tile = w >> 4;
  int fbase = (w & 15) * 128;
  if(tile >= c->ntiles) return;
  int e = c->texp[tile];
  int base = tile*TM;
  int tid = threadIdx.x;

  int r0 = tid>>3;
  int cs = (tid&7) ^ (r0&7);
  int t0 = etok[base + r0];
  int t1 = etok[base + 64 + r0];
  int t2 = etok[base + 128 + r0];
  int t3 = etok[base + 192 + r0];
  const unsigned short* sA0 = Xb + (size_t)t0*D_MODEL + cs*8;
  const unsigned short* sA1 = Xb + (size_t)t1*D_MODEL + cs*8;
  const unsigned short* sA2 = Xb + (size_t)t2*D_MODEL + cs*8;
  const unsigned short* sA3 = Xb + (size_t)t3*D_MODEL + cs*8;
  const unsigned short* WE = W1b + (size_t)e*(D_FF*D_MODEL);
  const unsigned short* VE = V1b + (size_t)e*(D_FF*D_MODEL);
  const unsigned short* sB0 = WE + (size_t)(fbase+r0)*D_MODEL + cs*8;
  const unsigned short* sB1 = WE + (size_t)(fbase+64+r0)*D_MODEL + cs*8;
  const unsigned short* sB2 = VE + (size_t)(fbase+r0)*D_MODEL + cs*8;
  const unsigned short* sB3 = VE + (size_t)(fbase+64+r0)*D_MODEL + cs*8;
  int w64 = tid & ~63;

  int lane = tid&63, lrow = lane&15, lk = lane>>4;
  int wid = tid>>6, wr = wid>>2, wc = wid&3;
  int sw = lrow&7;

  f32x4 hacc[8][2], vacc[8][2];
  #pragma unroll
  for(int mi=0;mi<8;mi++)
    #pragma unroll
    for(int nj=0;nj<2;nj++){
      hacc[mi][nj]=(f32x4){0.f,0.f,0.f,0.f};
      vacc[mi][nj]=(f32x4){0.f,0.f,0.f,0.f};
    }

  auto STAGE = [&](int b, int t){
    size_t off = (size_t)t*BK;
    gload16(sA0+off, &As[b][w64]);
    gload16(sA1+off, &As[b][512+w64]);
    gload16(sA2+off, &As[b][1024+w64]);
    gload16(sA3+off, &As[b][1536+w64]);
    gload16(sB0+off, &Bs[b][w64]);
    gload16(sB1+off, &Bs[b][512+w64]);
    gload16(sB2+off, &Bs[b][1024+w64]);
    gload16(sB3+off, &Bs[b][1536+w64]);
  };

  STAGE(0,0);
  for(int t=0;t<8;t++){
    int cur = t&1;
    if(t<7) STAGE(cur^1, t+1);
    PIPE_WAIT_N("8", t==7);
    #pragma unroll
    for(int kk=0;kk<2;kk++){
      int ch = (kk*4+lk) ^ sw;
      short8 a[8], bw[2], bv[2];
      #pragma unroll
      for(int mi=0;mi<8;mi++)
        a[mi] = As[cur][(wr*128+mi*16+lrow)*8 + ch];
      #pragma unroll
      for(int nj=0;nj<2;nj++){
        int fr = wc*32+nj*16+lrow;
        bw[nj] = Bs[cur][fr*8 + ch];
        bv[nj] = Bs[cur][1024 + fr*8 + ch];
      }
      #pragma unroll
      for(int mi=0;mi<8;mi++)
        #pragma unroll
        for(int nj=0;nj<2;nj++){
          hacc[mi][nj] = __builtin_amdgcn_mfma_f32_16x16x32_bf16(a[mi], bw[nj], hacc[mi][nj],0,0,0);
          vacc[mi][nj] = __builtin_amdgcn_mfma_f32_16x16x32_bf16(a[mi], bv[nj], vacc[mi][nj],0,0,0);
        }
    }
    PIPE_END();
  }

  #pragma unroll
  for(int mi=0;mi<8;mi++){
    int m = base + wr*128 + mi*16 + lk*4;
    #pragma unroll
    for(int nj=0;nj<2;nj++){
      int f = fbase + wc*32 + nj*16 + lrow;
      #pragma unroll
      for(int r=0;r<4;r++){
        float h = hacc[mi][nj][r], vv = vacc[mi][nj][r];
        float g = (h/(1.0f+__expf(-h)))*vv;
        G[(size_t)(m+r)*D_FF + f] = f2bf(g);
      }
    }
  }
}

// ---------------- phase B: Ye = G W2^T (per-entry rows, no atomics) ----------------
// tile = 128 entries x 256 n-cols, K=2048 (32 dbuf steps). 8 waves (2M x 4N), wave = 64x64.
__global__ void __launch_bounds__(512,2)
expB_kernel(const unsigned short* __restrict__ G, const unsigned short* __restrict__ W2b,
            const Ctrl* __restrict__ c, unsigned short* __restrict__ Ye){
  __shared__ short8 As2[2][1024];  // 128 rows x 8 chunks
  __shared__ short8 Bs2[2][2048];  // 256 rows x 8 chunks
  int bid = blockIdx.x;                 // 0..287, 288 = 8*36
  int w = (bid & 7)*36 + (bid >> 3);    // XCD-chunked bijective swizzle
  int tileB = w >> 1;
  int nb = w & 1;
  if(tileB >= (c->offpad[8] >> 7)) return;
  int e = c->texp[tileB>>1];
  int base = tileB*128;
  int nbase = nb*256;
  int tid = threadIdx.x;

  int r0 = tid>>3;
  int cs = (tid&7) ^ (r0&7);
  const unsigned short* sA0 = G + (size_t)(base+r0)*D_FF + cs*8;
  const unsigned short* sA1 = G + (size_t)(base+64+r0)*D_FF + cs*8;
  const unsigned short* W2E = W2b + (size_t)e*(D_MODEL*D_FF);
  const unsigned short* sB0 = W2E + (size_t)(nbase+r0)*D_FF + cs*8;
  const unsigned short* sB1 = W2E + (size_t)(nbase+64+r0)*D_FF + cs*8;
  const unsigned short* sB2 = W2E + (size_t)(nbase+128+r0)*D_FF + cs*8;
  const unsigned short* sB3 = W2E + (size_t)(nbase+192+r0)*D_FF + cs*8;
  int w64 = tid & ~63;

  int lane = tid&63, lrow = lane&15, lk = lane>>4;
  int wid = tid>>6, wr = wid>>2, wc = wid&3;
  int sw = lrow&7;

  f32x4 acc[4][4];
  #pragma unroll
  for(int mi=0;mi<4;mi++)
    #pragma unroll
    for(int nj=0;nj<4;nj++) acc[mi][nj]=(f32x4){0.f,0.f,0.f,0.f};

  auto STAGE = [&](int b, int t){
    size_t off = (size_t)t*BK;
    gload16(sA0+off, &As2[b][w64]);
    gload16(sA1+off, &As2[b][512+w64]);
    gload16(sB0+off, &Bs2[b][w64]);
    gload16(sB1+off, &Bs2[b][512+w64]);
    gload16(sB2+off, &Bs2[b][1024+w64]);
    gload16(sB3+off, &Bs2[b][1536+w64]);
  };

  STAGE(0,0);
  for(int t=0;t<32;t++){
    int cur = t&1;
    if(t<31) STAGE(cur^1, t+1);
    PIPE_WAIT_N("6", t==31);
    #pragma unroll
    for(int kk=0;kk<2;kk++){
      int ch = (kk*4+lk) ^ sw;
      short8 a[4], b[4];
      #pragma unroll
      for(int mi=0;mi<4;mi++)
        a[mi] = As2[cur][(wr*64+mi*16+lrow)*8 + ch];
      #pragma unroll
      for(int nj=0;nj<4;nj++)
        b[nj] = Bs2[cur][(wc*64+nj*16+lrow)*8 + ch];
      #pragma unroll
      for(int mi=0;mi<4;mi++)
        #pragma unroll
        for(int nj=0;nj<4;nj++)
          acc[mi][nj] = __builtin_amdgcn_mfma_f32_16x16x32_bf16(a[mi], b[nj], acc[mi][nj],0,0,0);
    }
    PIPE_END();
  }

  #pragma unroll
  for(int mi=0;mi<4;mi++){
    #pragma unroll
    for(int r=0;r<4;r++){
      int m = base + wr*64 + mi*16 + lk*4 + r;
      #pragma unroll
      for(int nj=0;nj<4;nj++){
        int n = nbase + wc*64 + nj*16 + lrow;
        Ye[(size_t)m*D_MODEL + n] = f2bf(acc[mi][nj][r]);
      }
    }
  }
}

// ---------------- combine: out[t] = s0*Ye[p0] + s1*Ye[p1] ----------------
__global__ void __launch_bounds__(256)
combine_kernel(const unsigned short* __restrict__ Ye, const int* __restrict__ pos,
               const float* __restrict__ tok_s, float* __restrict__ out){
  int wave = threadIdx.x>>6, lane = threadIdx.x&63;
  int t = blockIdx.x*4 + wave;
  int p0 = pos[2*t], p1 = pos[2*t+1];
  float s0 = tok_s[2*t], s1 = tok_s[2*t+1];
  short8 y0 = *(const short8*)(Ye + (size_t)p0*D_MODEL + lane*8);
  short8 y1 = *(const short8*)(Ye + (size_t)p1*D_MODEL + lane*8);
  float* o = out + (size_t)t*D_MODEL + lane*8;
  float4 lo, hi;
  lo.x = s0*bf2f((unsigned short)y0[0]) + s1*bf2f((unsigned short)y1[0]);
  lo.y = s0*bf2f((unsigned short)y0[1]) + s1*bf2f((unsigned short)y1[1]);
  lo.z = s0*bf2f((unsigned short)y0[2]) + s1*bf2f((unsigned short)y1[2]);
  lo.w = s0*bf2f((unsigned short)y0[3]) + s1*bf2f((unsigned short)y1[3]);
  hi.x = s0*bf2f((unsigned short)y0[4]) + s1*bf2f((unsigned short)y1[4]);
  hi.y = s0*bf2f((unsigned short)y0[5]) + s1*bf2f((unsigned short)y1[5]);
  hi.z = s0*bf2f((unsigned short)y0[6]) + s1*bf2f((unsigned short)y1[6]);
  hi.w = s0*bf2f((unsigned short)y0[7]) + s1*bf2f((unsigned short)y1[7]);
  *(float4*)o = lo;
  *(float4*)(o+4) = hi;
}

extern "C" void kernel_launch(void* const* d_in, const int* in_sizes, int n_in,
                              void* d_out, int out_size, void* d_ws, size_t ws_size,
                              hipStream_t stream) {
  (void)in_sizes; (void)n_in; (void)out_size;
  const float* x  = (const float*)d_in[0];
  const float* gw = (const float*)d_in[1];
  const float* W1 = (const float*)d_in[2];
  const float* V1 = (const float*)d_in[3];
  const float* W2 = (const float*)d_in[4];
  float* out = (float*)d_out;

  const size_t WSZ = (size_t)N_EXP*D_FF*D_MODEL;     // 8.39M elems per weight
  const size_t XSZ = (size_t)NTOK*D_MODEL;           // 4.19M
  char* ws = (char*)d_ws;
  size_t off = 0;
  unsigned short* W1b = (unsigned short*)(ws+off); off += WSZ*2;
  unsigned short* V1b = (unsigned short*)(ws+off); size_t v1_off = off; off += WSZ*2;
  unsigned short* Xb  = (unsigned short*)(ws+off); off += XSZ*2;
  unsigned short* G   = (unsigned short*)(ws+off); off += (size_t)NEPAD*D_FF*2;
  int*   etok  = (int*)(ws+off);   size_t entry_off = off; off += (size_t)NEPAD*4;
  float* escl  = (float*)(ws+off); off += (size_t)NEPAD*4;
  size_t entry_bytes = off - entry_off;
  int*   pos   = (int*)(ws+off);   off += (size_t)NTOK*2*4;
  int*   tok_e = (int*)(ws+off);   off += (size_t)NTOK*2*4;
  float* tok_s = (float*)(ws+off); off += (size_t)NTOK*2*4;
  float* Ppart = (float*)(ws+off); off += (size_t)2048*8*4;
  Ctrl*  ctrl  = (Ctrl*)(ws+off);  off += sizeof(Ctrl);
  unsigned short* W2b = W1b;                          // reuse after expA
  unsigned short* Ye  = (unsigned short*)(ws+v1_off); // reuse V1b+Xb after expA (18.9MB < 25.2MB)
  if(ws_size < off) return;

  hipMemsetAsync(ws+entry_off, 0, entry_bytes, stream);
  hipMemsetAsync(ctrl, 0, sizeof(Ctrl), stream);

  int nw = (int)WSZ;
  cvt_kernel<<<nw/(256*8), 256, 0, stream>>>(W1, W1b, nw);
  cvt_kernel<<<nw/(256*8), 256, 0, stream>>>(V1, V1b, nw);

  gate_kernel<<<NTOK/4, 256, 0, stream>>>(x, gw, tok_e, tok_s, ctrl, Ppart, Xb);
  scan_kernel<<<1, 256, 0, stream>>>(ctrl, Ppart, out);
  scatter_kernel<<<NTOK/256, 256, 0, stream>>>(tok_e, tok_s, ctrl, etok, escl, pos);

  expA_kernel<<<1152, 512, 0, stream>>>(Xb, W1b, V1b, etok, ctrl, G);
  cvt_kernel<<<nw/(256*8), 256, 0, stream>>>(W2, W2b, nw);   // into W1b region
  expB_kernel<<<288, 512, 0, stream>>>(G, W2b, ctrl, Ye);
  combine_kernel<<<NTOK/4, 256, 0, stream>>>(Ye, pos, tok_s, out);
}